// Round 9
// baseline (890.915 us; speedup 1.0000x reference)
//
#include <hip/hip_runtime.h>

// Problem constants (from reference)
#define I_CNT 100000
#define U_CNT 131072
#define E_DIM 64
#define IE (I_CNT * E_DIM)          // 6,400,000 floats
#define UE ((size_t)U_CNT * E_DIM)  // 8,388,608 floats

#define CHUNK 32  // edges per wave

// ---------------- threefry2x32 (verified vs Random123 test vector) ----------------
__device__ __forceinline__ unsigned rotl32(unsigned v, int n) {
    return (v << n) | (v >> (32 - n));
}
__device__ __forceinline__ void threefry2x32(unsigned k0, unsigned k1,
                                             unsigned x0, unsigned x1,
                                             unsigned& o0, unsigned& o1) {
    unsigned k2 = k0 ^ k1 ^ 0x1BD11BDAu;
    x0 += k0; x1 += k1;
#define RND(r) { x0 += x1; x1 = rotl32(x1, r); x1 ^= x0; }
    RND(13) RND(15) RND(26) RND(6)   x0 += k1; x1 += k2 + 1u;
    RND(17) RND(29) RND(16) RND(24)  x0 += k2; x1 += k0 + 2u;
    RND(13) RND(15) RND(26) RND(6)   x0 += k0; x1 += k1 + 3u;
    RND(17) RND(29) RND(16) RND(24)  x0 += k1; x1 += k2 + 4u;
    RND(13) RND(15) RND(26) RND(6)   x0 += k2; x1 += k0 + 5u;
#undef RND
    o0 = x0; o1 = x1;
}

// Dropout mask, MEASURED (R8 discriminator probe, exact match at 212.5):
// partitionable threefry, ctr=(0,e), bits = out0 ^ out1 (XOR fold),
// u = bitcast((bits>>9)|0x3f800000)-1; keep iff u < 0.8; rescale 1/0.8.
__device__ __forceinline__ float dropout_mul(unsigned e) {
    unsigned o0, o1;
    threefry2x32(0u, 42u, 0u, e, o0, o1);
    const unsigned bits = o0 ^ o1;
    const float u = __uint_as_float((bits >> 9) | 0x3f800000u) - 1.0f;
    return (u < 0.8f) ? 1.25f : 0.0f;
}

// ---------------- segmented COO SpMM (rows sorted), no dropout ----------------
// One wave handles CHUNK consecutive edges; lane = embedding dim (E=64=wave).
// Register accumulation while the row stays constant; atomicAdd at boundaries.
__global__ void spmm_seg_kernel(const float* __restrict__ vals,
                                const int* __restrict__ rows,
                                const int* __restrict__ cols,
                                const float* __restrict__ x,
                                float* __restrict__ y,
                                int nnz) {
    const int lane = threadIdx.x & 63;
    const int wave = blockIdx.x * (blockDim.x >> 6) + (threadIdx.x >> 6);
    long base = (long)wave * CHUNK;
    if (base >= nnz) return;
    long endl = base + CHUNK;
    if (endl > nnz) endl = nnz;
    const int end = (int)endl;

    int e = (int)base;
    int cur = rows[e];
    float acc = 0.0f;
    for (; e < end; ++e) {
        const int   r = rows[e];
        const int   c = cols[e];
        const float v = vals[e];
        const float xv = x[(size_t)c * E_DIM + lane];
        if (r != cur) {  // wave-uniform branch
            atomicAdd(&y[(size_t)cur * E_DIM + lane], acc);
            acc = 0.0f;
            cur = r;
        }
        acc = fmaf(v, xv, acc);
    }
    atomicAdd(&y[(size_t)cur * E_DIM + lane], acc);
}

// ---------------- URM SpMM with inline threefry-XOR dropout ----------------
// Lanes 0..31 compute multipliers for the wave's 32 edges in parallel;
// the serial edge loop broadcasts lane j's value via __shfl.
__global__ void spmm_urm_kernel(const float* __restrict__ vals,
                                const int* __restrict__ rows,
                                const int* __restrict__ cols,
                                const float* __restrict__ x,
                                float* __restrict__ y,
                                int nnz) {
    const int lane = threadIdx.x & 63;
    const int wave = blockIdx.x * (blockDim.x >> 6) + (threadIdx.x >> 6);
    long base = (long)wave * CHUNK;
    if (base >= nnz) return;
    long endl = base + CHUNK;
    if (endl > nnz) endl = nnz;
    const int end = (int)endl;

    const float keepmul = dropout_mul((unsigned)base + (unsigned)(lane & 31));

    int e = (int)base;
    int cur = rows[e];
    float acc = 0.0f;
    for (; e < end; ++e) {
        const float m = __shfl(keepmul, e - (int)base);
        const int   r = rows[e];
        const int   c = cols[e];
        const float v = vals[e] * m;
        const float xv = x[(size_t)c * E_DIM + lane];
        if (r != cur) {
            atomicAdd(&y[(size_t)cur * E_DIM + lane], acc);
            acc = 0.0f;
            cur = r;
        }
        acc = fmaf(v, xv, acc);
    }
    atomicAdd(&y[(size_t)cur * E_DIM + lane], acc);
}

static inline int spmm_blocks(int nnz) {
    int nwaves = (nnz + CHUNK - 1) / CHUNK;
    return (nwaves + 3) / 4;  // 4 waves (256 threads) per block
}

extern "C" void kernel_launch(void* const* d_in, const int* in_sizes, int n_in,
                              void* d_out, int out_size, void* d_ws, size_t ws_size,
                              hipStream_t stream) {
    const float* item_emb = (const float*)d_in[0];
    const float* S_vals   = (const float*)d_in[1];
    const int*   S_rows   = (const int*)  d_in[2];
    const int*   S_cols   = (const int*)  d_in[3];
    const float* urm_vals = (const float*)d_in[4];
    const int*   urm_rows = (const int*)  d_in[5];
    const int*   urm_cols = (const int*)  d_in[6];

    const int nnzS = in_sizes[1];
    const int nnzU = in_sizes[4];

    float* user_out = (float*)d_out;          // U*E floats (output 0)
    float* x_out    = (float*)d_out + UE;     // I*E floats (output 1)

    const dim3 blk(256);

    // hop 1: item_emb -> x_out (x1)
    hipMemsetAsync(x_out, 0, (size_t)IE * sizeof(float), stream);
    spmm_seg_kernel<<<spmm_blocks(nnzS), blk, 0, stream>>>(
        S_vals, S_rows, S_cols, item_emb, x_out, nnzS);

    // hop 2: x_out -> user region (x2; IE < UE, fits)
    hipMemsetAsync(user_out, 0, (size_t)IE * sizeof(float), stream);
    spmm_seg_kernel<<<spmm_blocks(nnzS), blk, 0, stream>>>(
        S_vals, S_rows, S_cols, x_out, user_out, nnzS);

    // hop 3: user region (x2) -> x_out (x3 = final x output)
    hipMemsetAsync(x_out, 0, (size_t)IE * sizeof(float), stream);
    spmm_seg_kernel<<<spmm_blocks(nnzS), blk, 0, stream>>>(
        S_vals, S_rows, S_cols, user_out, x_out, nnzS);

    // user embeddings: URM_dropout @ x3
    hipMemsetAsync(user_out, 0, UE * sizeof(float), stream);
    spmm_urm_kernel<<<spmm_blocks(nnzU), blk, 0, stream>>>(
        urm_vals, urm_rows, urm_cols, x_out, user_out, nnzU);
}

// Round 10
// 450.681 us; speedup vs baseline: 1.9768x; 1.9768x over previous
//
#include <hip/hip_runtime.h>

// Problem constants (from reference)
#define I_CNT 100000
#define U_CNT 131072
#define E_DIM 64
#define IE (I_CNT * E_DIM)          // 6,400,000 floats
#define UE ((size_t)U_CNT * E_DIM)  // 8,388,608 floats

#define CHUNK 32  // edges per wave (32 index pairs preloaded by 64 lanes)
#define DEPTH 8   // outstanding x-gathers per wave (software pipeline ring)

// ---------------- threefry2x32 (verified vs Random123 test vector) ----------------
__device__ __forceinline__ unsigned rotl32(unsigned v, int n) {
    return (v << n) | (v >> (32 - n));
}
__device__ __forceinline__ void threefry2x32(unsigned k0, unsigned k1,
                                             unsigned x0, unsigned x1,
                                             unsigned& o0, unsigned& o1) {
    unsigned k2 = k0 ^ k1 ^ 0x1BD11BDAu;
    x0 += k0; x1 += k1;
#define RND(r) { x0 += x1; x1 = rotl32(x1, r); x1 ^= x0; }
    RND(13) RND(15) RND(26) RND(6)   x0 += k1; x1 += k2 + 1u;
    RND(17) RND(29) RND(16) RND(24)  x0 += k2; x1 += k0 + 2u;
    RND(13) RND(15) RND(26) RND(6)   x0 += k0; x1 += k1 + 3u;
    RND(17) RND(29) RND(16) RND(24)  x0 += k1; x1 += k2 + 4u;
    RND(13) RND(15) RND(26) RND(6)   x0 += k2; x1 += k0 + 5u;
#undef RND
    o0 = x0; o1 = x1;
}

// Dropout mask, MEASURED (R8 discriminator probe, exact hit at 212.5):
// partitionable threefry, ctr=(0,e), bits = out0 ^ out1 (XOR fold),
// u = bitcast((bits>>9)|0x3f800000)-1; keep iff u < 0.8; rescale 1/0.8.
__device__ __forceinline__ float dropout_mul(unsigned e) {
    unsigned o0, o1;
    threefry2x32(0u, 42u, 0u, e, o0, o1);
    const unsigned bits = o0 ^ o1;
    const float u = __uint_as_float((bits >> 9) | 0x3f800000u) - 1.0f;
    return (u < 0.8f) ? 1.25f : 0.0f;
}

// ---------------- segmented COO SpMM (rows sorted) ----------------
// One wave = CHUNK consecutive edges; lane = embedding dim (E=64=wave width).
// Fast path: indices preloaded in one coalesced load (lanes 0-31 rows,
// lanes 32-63 cols), broadcast via compile-time __shfl (-> readlane/SGPR);
// x-gathers software-pipelined DEPTH deep for MLP; register accumulation
// while the row stays constant; coalesced 256B atomic burst at boundaries.
template <bool DROPOUT>
__global__ void spmm_kernel(const float* __restrict__ vals,
                            const int* __restrict__ rows,
                            const int* __restrict__ cols,
                            const float* __restrict__ x,
                            float* __restrict__ y,
                            int nnz) {
    const int lane = threadIdx.x & 63;
    const int wave = blockIdx.x * (blockDim.x >> 6) + (threadIdx.x >> 6);
    const long base = (long)wave * CHUNK;
    if (base >= nnz) return;

    if (base + CHUNK <= nnz) {
        // ---- fast path: full chunk ----
        const int j = lane & 31;
        const int idx = (lane < 32) ? rows[base + j] : cols[base + j];
        float v = vals[base + j];
        if (DROPOUT) v *= dropout_mul((unsigned)(base + j));

        float xv[DEPTH];
#pragma unroll
        for (int u = 0; u < DEPTH; ++u) {
            const int c = __shfl(idx, 32 + u);
            xv[u] = x[(size_t)c * E_DIM + lane];
        }

        int cur = __shfl(idx, 0);
        float acc = 0.0f;
#pragma unroll
        for (int e = 0; e < CHUNK; ++e) {
            const float xc = xv[e % DEPTH];
            if (e + DEPTH < CHUNK) {  // refill ring slot
                const int c = __shfl(idx, 32 + e + DEPTH);
                xv[e % DEPTH] = x[(size_t)c * E_DIM + lane];
            }
            const int   r  = __shfl(idx, e);     // wave-uniform row
            const float vv = __shfl(v, e);       // wave-uniform value
            if (r != cur) {
                atomicAdd(&y[(size_t)cur * E_DIM + lane], acc);
                acc = 0.0f;
                cur = r;
            }
            acc = fmaf(vv, xc, acc);
        }
        atomicAdd(&y[(size_t)cur * E_DIM + lane], acc);
    } else {
        // ---- tail path (nnz % CHUNK != 0; absent for these shapes) ----
        int e = (int)base;
        int cur = rows[e];
        float acc = 0.0f;
        for (; e < nnz; ++e) {
            float v = vals[e];
            if (DROPOUT) v *= dropout_mul((unsigned)e);
            const int   c  = cols[e];
            const float xc = x[(size_t)c * E_DIM + lane];
            const int   r  = rows[e];
            if (r != cur) {
                atomicAdd(&y[(size_t)cur * E_DIM + lane], acc);
                acc = 0.0f;
                cur = r;
            }
            acc = fmaf(v, xc, acc);
        }
        atomicAdd(&y[(size_t)cur * E_DIM + lane], acc);
    }
}

static inline int spmm_blocks(int nnz) {
    int nwaves = (nnz + CHUNK - 1) / CHUNK;
    return (nwaves + 3) / 4;  // 4 waves (256 threads) per block
}

extern "C" void kernel_launch(void* const* d_in, const int* in_sizes, int n_in,
                              void* d_out, int out_size, void* d_ws, size_t ws_size,
                              hipStream_t stream) {
    const float* item_emb = (const float*)d_in[0];
    const float* S_vals   = (const float*)d_in[1];
    const int*   S_rows   = (const int*)  d_in[2];
    const int*   S_cols   = (const int*)  d_in[3];
    const float* urm_vals = (const float*)d_in[4];
    const int*   urm_rows = (const int*)  d_in[5];
    const int*   urm_cols = (const int*)  d_in[6];

    const int nnzS = in_sizes[1];
    const int nnzU = in_sizes[4];

    float* user_out = (float*)d_out;          // U*E floats (output 0)
    float* x_out    = (float*)d_out + UE;     // I*E floats (output 1)

    const dim3 blk(256);

    // hop 1: item_emb -> x_out (x1)
    hipMemsetAsync(x_out, 0, (size_t)IE * sizeof(float), stream);
    spmm_kernel<false><<<spmm_blocks(nnzS), blk, 0, stream>>>(
        S_vals, S_rows, S_cols, item_emb, x_out, nnzS);

    // hop 2: x_out -> user region (x2; IE < UE, fits)
    hipMemsetAsync(user_out, 0, (size_t)IE * sizeof(float), stream);
    spmm_kernel<false><<<spmm_blocks(nnzS), blk, 0, stream>>>(
        S_vals, S_rows, S_cols, x_out, user_out, nnzS);

    // hop 3: user region (x2) -> x_out (x3 = final x output)
    hipMemsetAsync(x_out, 0, (size_t)IE * sizeof(float), stream);
    spmm_kernel<false><<<spmm_blocks(nnzS), blk, 0, stream>>>(
        S_vals, S_rows, S_cols, user_out, x_out, nnzS);

    // user embeddings: URM_dropout @ x3
    hipMemsetAsync(user_out, 0, UE * sizeof(float), stream);
    spmm_kernel<true><<<spmm_blocks(nnzU), blk, 0, stream>>>(
        urm_vals, urm_rows, urm_cols, x_out, user_out, nnzU);
}